// Round 2
// baseline (34657.825 us; speedup 1.0000x reference)
//
#include <hip/hip_runtime.h>

typedef unsigned long long ull;

#define EMB 512
#define HID 1024
#define NV  32000
#define NB  4
#define NT  64
#define GSLOT (32*6144)

__device__ __forceinline__ ull umax64(ull a, ull b) { return a > b ? a : b; }
__device__ __forceinline__ ull umin64(ull a, ull b) { return a < b ? a : b; }

// Total-order key: larger value first, ties -> lower index (matches jax.lax.top_k)
__device__ __forceinline__ ull packkey(float v, unsigned idx) {
  unsigned u = __float_as_uint(v);
  u ^= (u >> 31) ? 0xFFFFFFFFu : 0x80000000u;
  return ((ull)u << 32) | (ull)(0xFFFFFFFFu - idx);
}

// ---------------------------------------------------------------------------
// prep: hT[k][n] = encoded[n/8][k]; embX[k][n] = emb[bos][k]
// ---------------------------------------------------------------------------
__global__ void k_prep(const float* __restrict__ encoded, const float* __restrict__ emb,
                       const int* __restrict__ bosp,
                       float* __restrict__ hT, float* __restrict__ embX)
{
  int g = blockIdx.x * 256 + threadIdx.x;   // 49152 = 32768 + 16384
  if (g < 32768) {
    int k = g >> 5, n = g & 31;
    hT[g] = encoded[(n >> 3) * HID + k];
  } else {
    int g2 = g - 32768;
    int k = g2 >> 5;
    embX[g2] = emb[(size_t)(*bosp) * EMB + k];
  }
}

// ---------------------------------------------------------------------------
// Single-wave register-tiled GEMM: out[n][j0+jl] (+=bias) = sum_k W[jl][k]*x[k][n]
// WG = 64 threads = 1 wave. Tile: 32 j x 32 n. Thread: 8 j x 2 n.
// W staged transposed in LDS (pitch 36 -> conflict-free), x staged [k][n].
// Double-buffered, prefetch to regs, no __syncthreads (single wave).
// ---------------------------------------------------------------------------
template<bool LSE>
__device__ __forceinline__ void gemm32(
    const float* __restrict__ Wrow,   // W + jw0*K  (32 rows of length K)
    int K,                            // row stride
    int kb0, int nchunks,             // k-range start, #chunks of 32
    const float* __restrict__ xT,     // [k][32] (full, not offset)
    float* __restrict__ outCol,       // out + j0  (row pitch = opitch)
    int opitch,
    const float* __restrict__ biasCol,// bias + j0, or nullptr
    float* __restrict__ lsePair)      // lsePart + wg*64, or nullptr
{
  __shared__ float wlds[2][32 * 36];
  __shared__ float xlds[2][32 * 32];

  const int t  = threadIdx.x;   // 0..63
  const int tj = t & 3;         // j-quad group (j = tj*8 + jb)
  const int tn = t >> 2;        // n-group (n = tn*2 + n')

  // staging source addresses
  const float* wsrc_base = Wrow + (size_t)(t >> 1) * K + (t & 1) * 16;

  float acc[8][2];
#pragma unroll
  for (int a = 0; a < 8; ++a) { acc[a][0] = 0.f; acc[a][1] = 0.f; }

  float4 wr[4], xr[4];
  // fetch chunk 0
  {
    const int kb = kb0;
    const float* ws = wsrc_base + kb;
    const float* xs = xT + (size_t)kb * 32;
#pragma unroll
    for (int q = 0; q < 4; ++q) wr[q] = *(const float4*)(ws + 4 * q);
#pragma unroll
    for (int q = 0; q < 4; ++q) xr[q] = *(const float4*)(xs + q * 256 + t * 4);
  }
  // store chunk 0 -> buf 0
  {
    const int klocal = (t & 1) * 16;
    const int row = t >> 1;
#pragma unroll
    for (int q = 0; q < 4; ++q) {
      wlds[0][(klocal + 4 * q + 0) * 36 + row] = wr[q].x;
      wlds[0][(klocal + 4 * q + 1) * 36 + row] = wr[q].y;
      wlds[0][(klocal + 4 * q + 2) * 36 + row] = wr[q].z;
      wlds[0][(klocal + 4 * q + 3) * 36 + row] = wr[q].w;
    }
#pragma unroll
    for (int q = 0; q < 4; ++q) *(float4*)(&xlds[0][q * 256 + t * 4]) = xr[q];
  }

  int buf = 0;
  for (int c = 0; c < nchunks; ++c) {
    const bool more = (c + 1 < nchunks);
    if (more) {
      const int kb = kb0 + (c + 1) * 32;
      const float* ws = wsrc_base + kb;
      const float* xs = xT + (size_t)kb * 32;
#pragma unroll
      for (int q = 0; q < 4; ++q) wr[q] = *(const float4*)(ws + 4 * q);
#pragma unroll
      for (int q = 0; q < 4; ++q) xr[q] = *(const float4*)(xs + q * 256 + t * 4);
    }
    // compute on buf
    {
      const float* wb = wlds[buf];
      const float* xb = xlds[buf];
#pragma unroll
      for (int k = 0; k < 32; ++k) {
        float4 w0 = *(const float4*)(wb + k * 36 + tj * 8);
        float4 w1 = *(const float4*)(wb + k * 36 + tj * 8 + 4);
        float2 xv = *(const float2*)(xb + k * 32 + tn * 2);
        acc[0][0] = fmaf(w0.x, xv.x, acc[0][0]); acc[0][1] = fmaf(w0.x, xv.y, acc[0][1]);
        acc[1][0] = fmaf(w0.y, xv.x, acc[1][0]); acc[1][1] = fmaf(w0.y, xv.y, acc[1][1]);
        acc[2][0] = fmaf(w0.z, xv.x, acc[2][0]); acc[2][1] = fmaf(w0.z, xv.y, acc[2][1]);
        acc[3][0] = fmaf(w0.w, xv.x, acc[3][0]); acc[3][1] = fmaf(w0.w, xv.y, acc[3][1]);
        acc[4][0] = fmaf(w1.x, xv.x, acc[4][0]); acc[4][1] = fmaf(w1.x, xv.y, acc[4][1]);
        acc[5][0] = fmaf(w1.y, xv.x, acc[5][0]); acc[5][1] = fmaf(w1.y, xv.y, acc[5][1]);
        acc[6][0] = fmaf(w1.z, xv.x, acc[6][0]); acc[6][1] = fmaf(w1.z, xv.y, acc[6][1]);
        acc[7][0] = fmaf(w1.w, xv.x, acc[7][0]); acc[7][1] = fmaf(w1.w, xv.y, acc[7][1]);
      }
    }
    if (more) {
      const int nb = buf ^ 1;
      const int klocal = (t & 1) * 16;
      const int row = t >> 1;
#pragma unroll
      for (int q = 0; q < 4; ++q) {
        wlds[nb][(klocal + 4 * q + 0) * 36 + row] = wr[q].x;
        wlds[nb][(klocal + 4 * q + 1) * 36 + row] = wr[q].y;
        wlds[nb][(klocal + 4 * q + 2) * 36 + row] = wr[q].z;
        wlds[nb][(klocal + 4 * q + 3) * 36 + row] = wr[q].w;
      }
#pragma unroll
      for (int q = 0; q < 4; ++q) *(float4*)(&xlds[nb][q * 256 + t * 4]) = xr[q];
    }
    buf ^= 1;
  }

  // epilogue: bias, store, lse partials
#pragma unroll
  for (int np = 0; np < 2; ++np) {
    const int n = tn * 2 + np;
    float v[8];
#pragma unroll
    for (int jb = 0; jb < 8; ++jb) {
      v[jb] = acc[jb][np];
      if (biasCol) v[jb] += biasCol[tj * 8 + jb];
    }
    *(float4*)(outCol + (size_t)n * opitch + tj * 8)     = make_float4(v[0], v[1], v[2], v[3]);
    *(float4*)(outCol + (size_t)n * opitch + tj * 8 + 4) = make_float4(v[4], v[5], v[6], v[7]);
    if (LSE) {
      float m = v[0];
#pragma unroll
      for (int jb = 1; jb < 8; ++jb) m = fmaxf(m, v[jb]);
      m = fmaxf(m, __shfl_xor(m, 1, 64));
      m = fmaxf(m, __shfl_xor(m, 2, 64));
      float s = 0.f;
#pragma unroll
      for (int jb = 0; jb < 8; ++jb) s += expf(v[jb] - m);
      s += __shfl_xor(s, 1, 64);
      s += __shfl_xor(s, 2, 64);
      if (tj == 0) {
        lsePair[n * 2]     = m;
        lsePair[n * 2 + 1] = s;
      }
    }
  }
}

// ---------------------------------------------------------------------------
// gates: 576 WGs. 0..383: hh (jt=bx%96, s=bx/96, K=1024 split 4x256)
//                 384..575: ih (jt=r%96, s=r/96, K=512 split 2x256)
// ---------------------------------------------------------------------------
__global__ __launch_bounds__(64) void k_gates(
    const float* __restrict__ Wih, const float* __restrict__ Whh,
    const float* __restrict__ embX, const float* __restrict__ hT,
    float* __restrict__ gatesP)
{
  const int bx = blockIdx.x;
  if (bx < 384) {
    const int s  = bx / 96;
    const int jt = bx - s * 96;
    const int j0 = 3072 + jt * 32;
    gemm32<false>(Whh + (size_t)jt * 32 * HID, HID, s * 256, 8, hT,
                  gatesP + (size_t)s * GSLOT + j0, 6144, nullptr, nullptr);
  } else {
    const int r  = bx - 384;
    const int s  = r / 96;
    const int jt = r - s * 96;
    const int j0 = jt * 32;
    gemm32<false>(Wih + (size_t)jt * 32 * EMB, EMB, s * 256, 8, embX,
                  gatesP + (size_t)s * GSLOT + j0, 6144, nullptr, nullptr);
  }
}

// ---------------------------------------------------------------------------
// combine: sum K-split partials + biases, GRU elementwise, h2T[k][n]
// ---------------------------------------------------------------------------
__global__ __launch_bounds__(256) void k_combine(
    const float* __restrict__ gatesP,
    const float* __restrict__ bih, const float* __restrict__ bhh,
    const float* __restrict__ hT, float* __restrict__ h2T)
{
  int g = blockIdx.x * 256 + threadIdx.x;   // 32768
  int n = g & 31, i = g >> 5;
  const float* P0 = gatesP + (size_t)n * 6144;
  const float* P1 = P0 + GSLOT;
  const float* P2 = P1 + GSLOT;
  const float* P3 = P2 + GSLOT;
  float gir = P0[i]        + P1[i]        + bih[i];
  float giz = P0[1024 + i] + P1[1024 + i] + bih[1024 + i];
  float gin = P0[2048 + i] + P1[2048 + i] + bih[2048 + i];
  float ghr = P0[3072 + i] + P1[3072 + i] + P2[3072 + i] + P3[3072 + i] + bhh[i];
  float ghz = P0[4096 + i] + P1[4096 + i] + P2[4096 + i] + P3[4096 + i] + bhh[1024 + i];
  float ghn = P0[5120 + i] + P1[5120 + i] + P2[5120 + i] + P3[5120 + i] + bhh[2048 + i];
  float r = 1.f / (1.f + expf(-(gir + ghr)));
  float z = 1.f / (1.f + expf(-(giz + ghz)));
  float nn = tanhf(gin + r * ghn);
  h2T[g] = (1.f - z) * nn + z * hT[g];
}

// ---------------------------------------------------------------------------
// logits: 1000 WGs of 64 threads; out logitsN[n][v] + bias + lse partials
// ---------------------------------------------------------------------------
__global__ __launch_bounds__(64) void k_logits(
    const float* __restrict__ Wout, const float* __restrict__ bout,
    const float* __restrict__ h2T, float* __restrict__ logitsN,
    float* __restrict__ lsePart)
{
  const int j0 = blockIdx.x * 32;
  gemm32<true>(Wout + (size_t)j0 * HID, HID, 0, 32, h2T,
               logitsN + j0, NV, bout + j0, lsePart + (size_t)blockIdx.x * 64);
}

// ---------------------------------------------------------------------------
// topk: one WG per batch. lse-finish -> scan -> merge -> commit + gathers +
// embX for next step.  logitsN layout [n][v] (v-contiguous scan).
// ---------------------------------------------------------------------------
__global__ __launch_bounds__(256) void k_topk(
    const float* __restrict__ logitsN, const float* __restrict__ lsePart,
    const float* __restrict__ emb, const int* __restrict__ eosp,
    float* __restrict__ prev_vals, int* __restrict__ prev_tok,
    const float* __restrict__ lp_src, float* __restrict__ lp_dst,
    const int* __restrict__ tok_src, int* __restrict__ tok_dst,
    const float* __restrict__ h2T, float* __restrict__ hT,
    float* __restrict__ embX,
    int step, int mode)
{
  const int t = threadIdx.x;
  const int b = blockIdx.x;

  __shared__ float pm[32][8];
  __shared__ float ps[32][8];
  __shared__ float A[8];
  __shared__ ull wm[4];
  __shared__ float vals8[8];
  __shared__ int tok8[8];
  __shared__ int which8[8];

  // phase 1: finish logsumexp over 1000 partials for rows b*8..b*8+7
  {
    const int n8 = t & 7;
    const int grp = t >> 3;
    float m = -3.0e38f, s = 0.f;
    for (int p = grp; p < 1000; p += 32) {
      float2 q = *(const float2*)(lsePart + (size_t)p * 64 + (b * 8 + n8) * 2);
      float Mx = fmaxf(m, q.x);
      s = s * expf(m - Mx) + q.y * expf(q.x - Mx);
      m = Mx;
    }
    pm[grp][n8] = m; ps[grp][n8] = s;
    __syncthreads();
    for (int off2 = 16; off2 >= 1; off2 >>= 1) {
      if (grp < off2) {
        float m1 = pm[grp][n8], s1 = ps[grp][n8];
        float m2 = pm[grp + off2][n8], s2 = ps[grp + off2][n8];
        float Mx = fmaxf(m1, m2);
        pm[grp][n8] = Mx;
        ps[grp][n8] = s1 * expf(m1 - Mx) + s2 * expf(m2 - Mx);
      }
      __syncthreads();
    }
    if (t < 8) A[t] = pm[0][t] + logf(ps[0][t]);
    __syncthreads();
  }

  const int eos = *eosp;
  float Al[8], pv[8]; int pt[8];
#pragma unroll
  for (int j = 0; j < 8; ++j) {
    Al[j] = A[j];
    pv[j] = prev_vals[b * 8 + j];
    pt[j] = prev_tok[b * 8 + j];
  }

  // phase 2: per-thread sorted top-8 over this batch's candidates
  ull t8[8];
#pragma unroll
  for (int j = 0; j < 8; ++j) t8[j] = 0ULL;

  if (mode == 1) {
    for (int kb = 0; kb < 8; ++kb) {
      const float* row = logitsN + (size_t)(b * 8 + kb) * NV;
      const bool fin = (pt[kb] == eos);
      const float add = pv[kb] - Al[kb];
      for (int it = 0; it < NV / 256; ++it) {
        int v = it * 256 + t;
        float val;
        if (fin) val = (v == eos) ? 0.f : -1e30f;
        else val = row[v] + add;
        ull key = packkey(val, (unsigned)(kb * NV + v));
        if (key > t8[7]) {
          t8[7] = key;
#pragma unroll
          for (int q = 7; q >= 1; --q) {
            ull hi = umax64(t8[q - 1], t8[q]);
            ull lo = umin64(t8[q - 1], t8[q]);
            t8[q - 1] = hi; t8[q] = lo;
          }
        }
      }
    }
  } else {
    const float* row = logitsN + (size_t)(b * 8) * NV;
    const float add = -Al[0];
    for (int it = 0; it < NV / 256; ++it) {
      int v = it * 256 + t;
      float val = row[v] + add;
      ull key = packkey(val, (unsigned)v);
      if (key > t8[7]) {
        t8[7] = key;
#pragma unroll
        for (int q = 7; q >= 1; --q) {
          ull hi = umax64(t8[q - 1], t8[q]);
          ull lo = umin64(t8[q - 1], t8[q]);
          t8[q - 1] = hi; t8[q] = lo;
        }
      }
    }
  }

  // phase 3: exact 8-round max extraction across the WG (keys unique)
  {
    int pi = 0;
    for (int r = 0; r < 8; ++r) {
      ull cand = (pi < 8) ? t8[pi] : 0ULL;
#pragma unroll
      for (int off = 1; off < 64; off <<= 1) cand = umax64(cand, __shfl_xor(cand, off, 64));
      if ((t & 63) == 0) wm[t >> 6] = cand;
      __syncthreads();
      ull win = umax64(umax64(wm[0], wm[1]), umax64(wm[2], wm[3]));
      if (pi < 8 && t8[pi] == win) ++pi;
      if (t == 0) {
        unsigned idx = 0xFFFFFFFFu - (unsigned)(win & 0xFFFFFFFFull);
        unsigned u = (unsigned)(win >> 32);
        u = (u >> 31) ? (u ^ 0x80000000u) : ~u;
        vals8[r] = __uint_as_float(u);
        if (mode == 1) { tok8[r] = (int)(idx % NV); which8[r] = (int)(idx / NV); }
        else { tok8[r] = (int)idx; which8[r] = r; }
      }
      __syncthreads();
    }
  }

  // phase 4: commit beam state + histories + hidden gather + embX build
  if (t < 8) {
    prev_vals[b * 8 + t] = vals8[t];
    prev_tok[b * 8 + t] = tok8[t];
  }
  for (int idx = t; idx < 512; idx += 256) {
    int j = idx >> 6;
    int tt = idx & 63;
    float lv; int tv;
    if (tt == step) { lv = vals8[j]; tv = tok8[j]; }
    else if (mode == 0) { lv = 0.f; tv = 0; }
    else {
      int w = which8[j];
      lv = lp_src[b * 512 + w * 64 + tt];
      tv = tok_src[b * 512 + w * 64 + tt];
    }
    lp_dst[b * 512 + idx] = lv;
    tok_dst[b * 512 + idx] = tv;
  }
  for (int idx = t; idx < 8192; idx += 256) {
    int kk = idx >> 3;
    int j = idx & 7;
    hT[kk * 32 + b * 8 + j] = h2T[kk * 32 + b * 8 + which8[j]];
  }
  // embX for next step: embX[k][b*8+j] = emb[tok8[j]][k]
  {
    int j = t >> 5;
    int kbase = (t & 31) * 16;
    const float* src = emb + (size_t)tok8[j] * EMB + kbase;
#pragma unroll
    for (int q = 0; q < 4; ++q) {
      float4 v = *(const float4*)(src + 4 * q);
      embX[(kbase + 4 * q + 0) * 32 + b * 8 + j] = v.x;
      embX[(kbase + 4 * q + 1) * 32 + b * 8 + j] = v.y;
      embX[(kbase + 4 * q + 2) * 32 + b * 8 + j] = v.z;
      embX[(kbase + 4 * q + 3) * 32 + b * 8 + j] = v.w;
    }
  }
}

// ---------------------------------------------------------------------------
// final: d_out = [lp_hist (2048 floats), tok_hist as floats (2048)]
// ---------------------------------------------------------------------------
__global__ void k_final(const float* __restrict__ lp_hist, const int* __restrict__ tok_hist,
                        float* __restrict__ out)
{
  int g = blockIdx.x * 256 + threadIdx.x;   // 4096
  if (g < 2048) out[g] = lp_hist[g];
  else out[g] = (float)tok_hist[g - 2048];
}

extern "C" void kernel_launch(void* const* d_in, const int* in_sizes, int n_in,
                              void* d_out, int out_size, void* d_ws, size_t ws_size,
                              hipStream_t stream)
{
  (void)in_sizes; (void)n_in; (void)out_size; (void)ws_size;
  const float* encoded   = (const float*)d_in[0];
  const float* embedding = (const float*)d_in[1];
  const float* Wih       = (const float*)d_in[2];
  const float* Whh       = (const float*)d_in[3];
  const float* bih       = (const float*)d_in[4];
  const float* bhh       = (const float*)d_in[5];
  const float* Wout      = (const float*)d_in[6];
  const float* bout      = (const float*)d_in[7];
  const int*   bosp      = (const int*)d_in[8];
  const int*   eosp      = (const int*)d_in[9];

  char* p = (char*)d_ws;
  size_t off = 0;
  auto ALLOC = [&](size_t bytes) -> void* {
    void* r = p + off;
    off += (bytes + 255) & ~(size_t)255;
    return r;
  };
  float* hT        = (float*)ALLOC((size_t)HID * 32 * 4);
  float* h2T       = (float*)ALLOC((size_t)HID * 32 * 4);
  float* embX      = (float*)ALLOC((size_t)EMB * 32 * 4);
  float* gatesP    = (float*)ALLOC((size_t)4 * GSLOT * 4);
  float* logitsN   = (float*)ALLOC((size_t)32 * NV * 4);
  float* lsePart   = (float*)ALLOC((size_t)1000 * 64 * 4);
  float* prev_vals = (float*)ALLOC(32 * 4);
  int*   prev_tok  = (int*)ALLOC(32 * 4);
  float* lp0       = (float*)ALLOC(2048 * 4);
  float* lp1       = (float*)ALLOC(2048 * 4);
  int*   tok0      = (int*)ALLOC(2048 * 4);
  int*   tok1      = (int*)ALLOC(2048 * 4);

  k_prep<<<192, 256, 0, stream>>>(encoded, embedding, bosp, hT, embX);
  for (int t = 0; t < NT; ++t) {
    k_gates<<<576, 64, 0, stream>>>(Wih, Whh, embX, hT, gatesP);
    k_combine<<<128, 256, 0, stream>>>(gatesP, bih, bhh, hT, h2T);
    k_logits<<<1000, 64, 0, stream>>>(Wout, bout, h2T, logitsN, lsePart);
    const int mode = (t == 0) ? 0 : 1;
    float* lps = (t & 1) ? lp0 : lp1;
    float* lpd = (t & 1) ? lp1 : lp0;
    int*   tks = (t & 1) ? tok0 : tok1;
    int*   tkd = (t & 1) ? tok1 : tok0;
    k_topk<<<NB, 256, 0, stream>>>(logitsN, lsePart, embedding, eosp,
                                   prev_vals, prev_tok, lps, lpd, tks, tkd,
                                   h2T, hT, embX, t, mode);
  }
  k_final<<<16, 256, 0, stream>>>(lp1, tok1, (float*)d_out);
}

// Round 3
// 34033.939 us; speedup vs baseline: 1.0183x; 1.0183x over previous
//
#include <hip/hip_runtime.h>

typedef unsigned long long ull;

#define EMB 512
#define HID 1024
#define NV  32000
#define NB  4
#define NT  64

__device__ __forceinline__ ull umax64(ull a, ull b) { return a > b ? a : b; }
__device__ __forceinline__ ull umin64(ull a, ull b) { return a < b ? a : b; }

// Total-order key: larger value first, ties -> lower index (matches jax.lax.top_k)
__device__ __forceinline__ ull packkey(float v, unsigned idx) {
  unsigned u = __float_as_uint(v);
  u ^= (u >> 31) ? 0xFFFFFFFFu : 0x80000000u;
  return ((ull)u << 32) | (ull)(0xFFFFFFFFu - idx);
}

// ---------------------------------------------------------------------------
// prep: hT[k][n] = encoded[n/8][k]; embX[k][n] = emb[bos][k]
// ---------------------------------------------------------------------------
__global__ void k_prep(const float* __restrict__ encoded, const float* __restrict__ emb,
                       const int* __restrict__ bosp,
                       float* __restrict__ hT, float* __restrict__ embX)
{
  int g = blockIdx.x * 256 + threadIdx.x;   // 49152 = 32768 + 16384
  if (g < 32768) {
    int k = g >> 5, n = g & 31;
    hT[g] = encoded[(n >> 3) * HID + k];
  } else {
    int g2 = g - 32768;
    int k = g2 >> 5;
    embX[g2] = emb[(size_t)(*bosp) * EMB + k];
  }
}

// ---------------------------------------------------------------------------
// GEMV-style GEMM core: WG = 256 threads (4 waves). WG computes
//   out[j0+j][n] = sum_k W[j][k] * x[k][n]   for j in [0,64), n in [0,32)
// Lane mapping: j = lane (64 j per wave); acc[32] per lane (one per n).
// x[k][*] is wave-uniform -> loaded via scalar (s_load) path into SGPRs.
// W staged per 32-k chunk into LDS transposed [k][j] (pitch 65, conflict-free).
// Waves split k within the chunk (8 k each); cross-wave LDS tree-reduction.
// TRANS=true: store out[n][j] into row-major [n][opitch] + optional LSE.
// TRANS=false: store out[j][n] (pitch 32) directly.
// ---------------------------------------------------------------------------
template<bool TRANS, bool LSE>
__device__ __forceinline__ void gemm_core(
    const float* __restrict__ Wrow,   // W + j0*K
    int K, int kb0, int nch,          // k-offset, #32-k chunks
    const float* __restrict__ xT,     // [k][32], must have >= 4KB slack after row kb0+nch*32
    const float* __restrict__ biasJ,  // bias + j0, or nullptr
    float* __restrict__ out,          // see TRANS
    int opitch,
    float* __restrict__ lsePair)      // lsePart + bx*64 (LSE only)
{
  __shared__ float wT[32 * 65];
  __shared__ float red[64 * 33];
  __shared__ float red2[64 * 33];

  const int t = threadIdx.x;
  const int l = t & 63;
  const int wq = __builtin_amdgcn_readfirstlane((int)threadIdx.x >> 6); // wave id, forced uniform

  // W staging: thread t loads row (t>>2), k-segment (t&3)*8 .. +7 (2 float4)
  const int wrow = t >> 2;
  const int wseg = t & 3;
  const float* wsrc = Wrow + (size_t)wrow * K + kb0 + wseg * 8;

  float acc[32];
#pragma unroll
  for (int n = 0; n < 32; ++n) acc[n] = 0.f;

  // x double-buffer (wave-uniform -> SGPRs)
  float xc[32], xn[32];
  {
    const float* xr = xT + (size_t)(kb0 + wq * 8) * 32;
#pragma unroll
    for (int n = 0; n < 32; ++n) xc[n] = xr[n];
  }

  float4 wa = *(const float4*)(wsrc);
  float4 wb = *(const float4*)(wsrc + 4);

  for (int c = 0; c < nch; ++c) {
    __syncthreads();
    {
      const int kl = wseg * 8;
      wT[(kl + 0) * 65 + wrow] = wa.x;
      wT[(kl + 1) * 65 + wrow] = wa.y;
      wT[(kl + 2) * 65 + wrow] = wa.z;
      wT[(kl + 3) * 65 + wrow] = wa.w;
      wT[(kl + 4) * 65 + wrow] = wb.x;
      wT[(kl + 5) * 65 + wrow] = wb.y;
      wT[(kl + 6) * 65 + wrow] = wb.z;
      wT[(kl + 7) * 65 + wrow] = wb.w;
    }
    if (c + 1 < nch) {
      wa = *(const float4*)(wsrc + (c + 1) * 32);
      wb = *(const float4*)(wsrc + (c + 1) * 32 + 4);
    }
    __syncthreads();

    // this wave's 8 W values (j = l) for its k-subset
    float wv[8];
#pragma unroll
    for (int kk = 0; kk < 8; ++kk) wv[kk] = wT[(wq * 8 + kk) * 65 + l];

#pragma unroll
    for (int kk = 0; kk < 8; ++kk) {
      // prefetch next x row (uniform address -> s_load); last one reads slack
      const int knext = (kk < 7) ? (c * 32 + wq * 8 + kk + 1) : ((c + 1) * 32 + wq * 8);
      const float* xr = xT + (size_t)(kb0 + knext) * 32;
#pragma unroll
      for (int n = 0; n < 32; ++n) xn[n] = xr[n];
      const float w = wv[kk];
#pragma unroll
      for (int n = 0; n < 32; ++n) acc[n] = fmaf(w, xc[n], acc[n]);
#pragma unroll
      for (int n = 0; n < 32; ++n) xc[n] = xn[n];
    }
  }

  // cross-wave reduction: red += contributions of all 4 waves
  if (wq == 0 || wq == 2) {
    float* r = (wq == 0) ? red : red2;
#pragma unroll
    for (int n = 0; n < 32; ++n) r[l * 33 + n] = acc[n];
  }
  __syncthreads();
  if (wq == 1 || wq == 3) {
    float* r = (wq == 1) ? red : red2;
#pragma unroll
    for (int n = 0; n < 32; ++n) r[l * 33 + n] += acc[n];
  }
  __syncthreads();
  for (int idx = t; idx < 64 * 33; idx += 256) red[idx] += red2[idx];
  __syncthreads();

  if (TRANS) {
    // thread t: n = t>>3 (0..31), jseg = t&7 (8 j each)
    const int n = t >> 3, jseg = t & 7;
    float v[8];
#pragma unroll
    for (int i = 0; i < 8; ++i) {
      v[i] = red[(jseg * 8 + i) * 33 + n];
      if (biasJ) v[i] += biasJ[jseg * 8 + i];
    }
    *(float4*)(out + (size_t)n * opitch + jseg * 8)     = make_float4(v[0], v[1], v[2], v[3]);
    *(float4*)(out + (size_t)n * opitch + jseg * 8 + 4) = make_float4(v[4], v[5], v[6], v[7]);
    if (LSE) {
      float m = v[0];
#pragma unroll
      for (int i = 1; i < 8; ++i) m = fmaxf(m, v[i]);
      m = fmaxf(m, __shfl_xor(m, 1, 64));
      m = fmaxf(m, __shfl_xor(m, 2, 64));
      m = fmaxf(m, __shfl_xor(m, 4, 64));
      float s = 0.f;
#pragma unroll
      for (int i = 0; i < 8; ++i) s += expf(v[i] - m);
      s += __shfl_xor(s, 1, 64);
      s += __shfl_xor(s, 2, 64);
      s += __shfl_xor(s, 4, 64);
      if (jseg == 0) {
        lsePair[n * 2]     = m;
        lsePair[n * 2 + 1] = s;
      }
    }
  } else {
    // thread t stores 8 contiguous elems of out[j][n]: j = t>>2, n0 = (t&3)*8
    const int j = t >> 2, n0 = (t & 3) * 8;
    float v[8];
#pragma unroll
    for (int q = 0; q < 8; ++q) v[q] = red[j * 33 + n0 + q];
    *(float4*)(out + (size_t)j * 32 + n0)     = make_float4(v[0], v[1], v[2], v[3]);
    *(float4*)(out + (size_t)j * 32 + n0 + 4) = make_float4(v[4], v[5], v[6], v[7]);
  }
}

// ---------------------------------------------------------------------------
// gates: bx 0..47: ih (j0=bx*64, K=512), out gatesI[j][n]
//        bx 48..143: hh, jt=(bx-48)%48, s=(bx-48)/48, K=1024 split 2x512,
//                    out gH[s][j][n]. Biases added in k_combine.
// ---------------------------------------------------------------------------
__global__ __launch_bounds__(256, 2) void k_gates(
    const float* __restrict__ Wih, const float* __restrict__ Whh,
    const float* __restrict__ embX, const float* __restrict__ hT,
    float* __restrict__ gatesI, float* __restrict__ gH)
{
  const int bx = blockIdx.x;
  if (bx < 48) {
    const int j0 = bx * 64;
    gemm_core<false, false>(Wih + (size_t)j0 * EMB, EMB, 0, 16, embX,
                            nullptr, gatesI + (size_t)j0 * 32, 0, nullptr);
  } else {
    const int r = bx - 48;
    const int s = r / 48;
    const int jt = r - s * 48;
    const int j0 = jt * 64;
    gemm_core<false, false>(Whh + (size_t)j0 * HID, HID, s * 512, 16, hT,
                            nullptr, gH + (size_t)s * (3072 * 32) + (size_t)j0 * 32, 0, nullptr);
  }
}

// ---------------------------------------------------------------------------
// combine: GRU elementwise; contiguous reads of gatesI/gH [j][n]
// ---------------------------------------------------------------------------
__global__ __launch_bounds__(256) void k_combine(
    const float* __restrict__ gatesI, const float* __restrict__ gH,
    const float* __restrict__ bih, const float* __restrict__ bhh,
    const float* __restrict__ hT, float* __restrict__ h2T)
{
  int g = blockIdx.x * 256 + threadIdx.x;   // 32768
  int n = g & 31, i = g >> 5;
  const float* gH0 = gH;
  const float* gH1 = gH + 3072 * 32;
  float gir = gatesI[g]                + bih[i];
  float giz = gatesI[(1024 << 5) + g]  + bih[1024 + i];
  float gin = gatesI[(2048 << 5) + g]  + bih[2048 + i];
  float ghr = gH0[g]               + gH1[g]               + bhh[i];
  float ghz = gH0[(1024 << 5) + g] + gH1[(1024 << 5) + g] + bhh[1024 + i];
  float ghn = gH0[(2048 << 5) + g] + gH1[(2048 << 5) + g] + bhh[2048 + i];
  float r = 1.f / (1.f + expf(-(gir + ghr)));
  float z = 1.f / (1.f + expf(-(giz + ghz)));
  float nn = tanhf(gin + r * ghn);
  h2T[g] = (1.f - z) * nn + z * hT[g];
}

// ---------------------------------------------------------------------------
// logits: 500 WGs; out logitsN[n][v] + bias + lse partials
// ---------------------------------------------------------------------------
__global__ __launch_bounds__(256, 2) void k_logits(
    const float* __restrict__ Wout, const float* __restrict__ bout,
    const float* __restrict__ h2T, float* __restrict__ logitsN,
    float* __restrict__ lsePart)
{
  const int j0 = blockIdx.x * 64;
  gemm_core<true, true>(Wout + (size_t)j0 * HID, HID, 0, 32, h2T,
                        bout + j0, logitsN + j0, NV,
                        lsePart + (size_t)blockIdx.x * 64);
}

// ---------------------------------------------------------------------------
// topk: one WG (256 thr) per batch. lse-finish -> scan -> merge -> commit +
// history gather + hidden gather + embX build for next step.
// ---------------------------------------------------------------------------
__global__ __launch_bounds__(256) void k_topk(
    const float* __restrict__ logitsN, const float* __restrict__ lsePart,
    const float* __restrict__ emb, const int* __restrict__ eosp,
    float* __restrict__ prev_vals, int* __restrict__ prev_tok,
    const float* __restrict__ lp_src, float* __restrict__ lp_dst,
    const int* __restrict__ tok_src, int* __restrict__ tok_dst,
    const float* __restrict__ h2T, float* __restrict__ hT,
    float* __restrict__ embX,
    int step, int mode)
{
  const int t = threadIdx.x;
  const int b = blockIdx.x;

  __shared__ float pm[32][8];
  __shared__ float ps[32][8];
  __shared__ float A[8];
  __shared__ ull wm[4];
  __shared__ float vals8[8];
  __shared__ int tok8[8];
  __shared__ int which8[8];

  // phase 1: finish logsumexp over 500 partials for rows b*8..b*8+7
  {
    const int n8 = t & 7;
    const int grp = t >> 3;
    float m = -3.0e38f, s = 0.f;
    for (int p = grp; p < 500; p += 32) {
      float2 q = *(const float2*)(lsePart + (size_t)p * 64 + (b * 8 + n8) * 2);
      float Mx = fmaxf(m, q.x);
      s = s * expf(m - Mx) + q.y * expf(q.x - Mx);
      m = Mx;
    }
    pm[grp][n8] = m; ps[grp][n8] = s;
    __syncthreads();
    for (int off2 = 16; off2 >= 1; off2 >>= 1) {
      if (grp < off2) {
        float m1 = pm[grp][n8], s1 = ps[grp][n8];
        float m2 = pm[grp + off2][n8], s2 = ps[grp + off2][n8];
        float Mx = fmaxf(m1, m2);
        pm[grp][n8] = Mx;
        ps[grp][n8] = s1 * expf(m1 - Mx) + s2 * expf(m2 - Mx);
      }
      __syncthreads();
    }
    if (t < 8) A[t] = pm[0][t] + logf(ps[0][t]);
    __syncthreads();
  }

  const int eos = *eosp;
  float Al[8], pv[8]; int pt[8];
#pragma unroll
  for (int j = 0; j < 8; ++j) {
    Al[j] = A[j];
    pv[j] = prev_vals[b * 8 + j];
    pt[j] = prev_tok[b * 8 + j];
  }

  // phase 2: per-thread sorted top-8
  ull t8[8];
#pragma unroll
  for (int j = 0; j < 8; ++j) t8[j] = 0ULL;

  if (mode == 1) {
    for (int kb = 0; kb < 8; ++kb) {
      const float* row = logitsN + (size_t)(b * 8 + kb) * NV;
      const bool fin = (pt[kb] == eos);
      const float add = pv[kb] - Al[kb];
      for (int it = 0; it < NV / 256; ++it) {
        int v = it * 256 + t;
        float val;
        if (fin) val = (v == eos) ? 0.f : -1e30f;
        else val = row[v] + add;
        ull key = packkey(val, (unsigned)(kb * NV + v));
        if (key > t8[7]) {
          t8[7] = key;
#pragma unroll
          for (int q = 7; q >= 1; --q) {
            ull hi = umax64(t8[q - 1], t8[q]);
            ull lo = umin64(t8[q - 1], t8[q]);
            t8[q - 1] = hi; t8[q] = lo;
          }
        }
      }
    }
  } else {
    const float* row = logitsN + (size_t)(b * 8) * NV;
    const float add = -Al[0];
    for (int it = 0; it < NV / 256; ++it) {
      int v = it * 256 + t;
      float val = row[v] + add;
      ull key = packkey(val, (unsigned)v);
      if (key > t8[7]) {
        t8[7] = key;
#pragma unroll
        for (int q = 7; q >= 1; --q) {
          ull hi = umax64(t8[q - 1], t8[q]);
          ull lo = umin64(t8[q - 1], t8[q]);
          t8[q - 1] = hi; t8[q] = lo;
        }
      }
    }
  }

  // phase 3: exact 8-round max extraction (keys unique)
  {
    int pi = 0;
    for (int r = 0; r < 8; ++r) {
      ull cand = (pi < 8) ? t8[pi] : 0ULL;
#pragma unroll
      for (int off = 1; off < 64; off <<= 1) cand = umax64(cand, __shfl_xor(cand, off, 64));
      if ((t & 63) == 0) wm[t >> 6] = cand;
      __syncthreads();
      ull win = umax64(umax64(wm[0], wm[1]), umax64(wm[2], wm[3]));
      if (pi < 8 && t8[pi] == win) ++pi;
      if (t == 0) {
        unsigned idx = 0xFFFFFFFFu - (unsigned)(win & 0xFFFFFFFFull);
        unsigned u = (unsigned)(win >> 32);
        u = (u >> 31) ? (u ^ 0x80000000u) : ~u;
        vals8[r] = __uint_as_float(u);
        if (mode == 1) { tok8[r] = (int)(idx % NV); which8[r] = (int)(idx / NV); }
        else { tok8[r] = (int)idx; which8[r] = r; }
      }
      __syncthreads();
    }
  }

  // phase 4: commit + gathers
  if (t < 8) {
    prev_vals[b * 8 + t] = vals8[t];
    prev_tok[b * 8 + t] = tok8[t];
  }
  for (int idx = t; idx < 512; idx += 256) {
    int j = idx >> 6;
    int tt = idx & 63;
    float lv; int tv;
    if (tt == step) { lv = vals8[j]; tv = tok8[j]; }
    else if (mode == 0) { lv = 0.f; tv = 0; }
    else {
      int w = which8[j];
      lv = lp_src[b * 512 + w * 64 + tt];
      tv = tok_src[b * 512 + w * 64 + tt];
    }
    lp_dst[b * 512 + idx] = lv;
    tok_dst[b * 512 + idx] = tv;
  }
  for (int idx = t; idx < 8192; idx += 256) {
    int kk = idx >> 3;
    int j = idx & 7;
    hT[kk * 32 + b * 8 + j] = h2T[kk * 32 + b * 8 + which8[j]];
  }
  // embX for next step: embX[k][b*8+j] = emb[tok8[j]][k]
  {
    int j = t >> 5;
    int kbase = (t & 31) * 16;
    const float* src = emb + (size_t)tok8[j] * EMB + kbase;
#pragma unroll
    for (int q = 0; q < 4; ++q) {
      float4 v = *(const float4*)(src + 4 * q);
      embX[(kbase + 4 * q + 0) * 32 + b * 8 + j] = v.x;
      embX[(kbase + 4 * q + 1) * 32 + b * 8 + j] = v.y;
      embX[(kbase + 4 * q + 2) * 32 + b * 8 + j] = v.z;
      embX[(kbase + 4 * q + 3) * 32 + b * 8 + j] = v.w;
    }
  }
}

// ---------------------------------------------------------------------------
// final: d_out = [lp_hist (2048 floats), tok_hist as floats (2048)]
// ---------------------------------------------------------------------------
__global__ void k_final(const float* __restrict__ lp_hist, const int* __restrict__ tok_hist,
                        float* __restrict__ out)
{
  int g = blockIdx.x * 256 + threadIdx.x;   // 4096
  if (g < 2048) out[g] = lp_hist[g];
  else out[g] = (float)tok_hist[g - 2048];
}

extern "C" void kernel_launch(void* const* d_in, const int* in_sizes, int n_in,
                              void* d_out, int out_size, void* d_ws, size_t ws_size,
                              hipStream_t stream)
{
  (void)in_sizes; (void)n_in; (void)out_size; (void)ws_size;
  const float* encoded   = (const float*)d_in[0];
  const float* embedding = (const float*)d_in[1];
  const float* Wih       = (const float*)d_in[2];
  const float* Whh       = (const float*)d_in[3];
  const float* bih       = (const float*)d_in[4];
  const float* bhh       = (const float*)d_in[5];
  const float* Wout      = (const float*)d_in[6];
  const float* bout      = (const float*)d_in[7];
  const int*   bosp      = (const int*)d_in[8];
  const int*   eosp      = (const int*)d_in[9];

  char* p = (char*)d_ws;
  size_t off = 0;
  auto ALLOC = [&](size_t bytes) -> void* {
    void* r = p + off;
    off += (bytes + 255) & ~(size_t)255;
    return r;
  };
  // x-buffers get 4KB slack (prefetch reads up to 25 rows past the end)
  float* hT        = (float*)ALLOC((size_t)HID * 32 * 4 + 4096);
  float* h2T       = (float*)ALLOC((size_t)HID * 32 * 4 + 4096);
  float* embX      = (float*)ALLOC((size_t)EMB * 32 * 4 + 4096);
  float* gatesI    = (float*)ALLOC((size_t)3072 * 32 * 4);
  float* gH       = (float*)ALLOC((size_t)2 * 3072 * 32 * 4);
  float* logitsN   = (float*)ALLOC((size_t)32 * NV * 4);
  float* lsePart   = (float*)ALLOC((size_t)500 * 64 * 4);
  float* prev_vals = (float*)ALLOC(32 * 4);
  int*   prev_tok  = (int*)ALLOC(32 * 4);
  float* lp0       = (float*)ALLOC(2048 * 4);
  float* lp1       = (float*)ALLOC(2048 * 4);
  int*   tok0      = (int*)ALLOC(2048 * 4);
  int*   tok1      = (int*)ALLOC(2048 * 4);

  k_prep<<<192, 256, 0, stream>>>(encoded, embedding, bosp, hT, embX);
  for (int t = 0; t < NT; ++t) {
    k_gates<<<144, 256, 0, stream>>>(Wih, Whh, embX, hT, gatesI, gH);
    k_combine<<<128, 256, 0, stream>>>(gatesI, gH, bih, bhh, hT, h2T);
    k_logits<<<500, 256, 0, stream>>>(Wout, bout, h2T, logitsN, lsePart);
    const int mode = (t == 0) ? 0 : 1;
    float* lps = (t & 1) ? lp0 : lp1;
    float* lpd = (t & 1) ? lp1 : lp0;
    int*   tks = (t & 1) ? tok0 : tok1;
    int*   tkd = (t & 1) ? tok1 : tok0;
    k_topk<<<NB, 256, 0, stream>>>(logitsN, lsePart, embedding, eosp,
                                   prev_vals, prev_tok, lps, lpd, tks, tkd,
                                   h2T, hT, embX, t, mode);
  }
  k_final<<<16, 256, 0, stream>>>(lp1, tok1, (float*)d_out);
}

// Round 4
// 6909.560 us; speedup vs baseline: 5.0159x; 4.9256x over previous
//
#include <hip/hip_runtime.h>

typedef unsigned long long ull;

#define EMB 512
#define HID 1024
#define NV  32000
#define NB  4
#define NT  64

__device__ __forceinline__ ull umax64(ull a, ull b) { return a > b ? a : b; }
__device__ __forceinline__ ull umin64(ull a, ull b) { return a < b ? a : b; }

// Total-order key: larger value first, ties -> lower index (matches jax.lax.top_k)
__device__ __forceinline__ ull packkey(float v, unsigned idx) {
  unsigned u = __float_as_uint(v);
  u ^= (u >> 31) ? 0xFFFFFFFFu : 0x80000000u;
  return ((ull)u << 32) | (ull)(0xFFFFFFFFu - idx);
}

// ---------------------------------------------------------------------------
// prep: hT[k][n] = encoded[n/8][k]; embX[k][n] = emb[bos][k]
// ---------------------------------------------------------------------------
__global__ void k_prep(const float* __restrict__ encoded, const float* __restrict__ emb,
                       const int* __restrict__ bosp,
                       float* __restrict__ hT, float* __restrict__ embX)
{
  int g = blockIdx.x * 256 + threadIdx.x;   // 49152 = 32768 + 16384
  if (g < 32768) {
    int k = g >> 5, n = g & 31;
    hT[g] = encoded[(n >> 3) * HID + k];
  } else {
    int g2 = g - 32768;
    int k = g2 >> 5;
    embX[g2] = emb[(size_t)(*bosp) * EMB + k];
  }
}

// ---------------------------------------------------------------------------
// GEMM panel core. WG = 256 thr (4 waves). WG computes
//   outP[j][n] partial = sum_{k in range} W[j][k] * x[k][n], j in [0,256), n in [0,32)
// x panel staged ONCE per section into LDS (broadcast ds_read_b128, conflict-
// free: 8 distinct addrs x 8-lane broadcast covering all 32 banks).
// W: each wave streams its own 64x16k chunks global->LDS-transposed [k][j]
// (double-buffered, private per wave -> no barriers in the K loop).
// Thread tile 8j x 4n. Per k: 2 b128 (W) + 1 b128 (x) + 32 v_fma -> VALU-bound.
// NO same-address global loads anywhere.
// ---------------------------------------------------------------------------
template<int SECK>
__device__ __forceinline__ void gemm_panel(
    const float* __restrict__ Wrow,   // W + j0*K (256 rows)
    int K,                            // W row stride
    int kb0, int nsec,                // k-range start, #sections of SECK
    const float* __restrict__ xT,     // [k][32] global
    float* __restrict__ outP)         // partial out + j0*32 (j-major, pitch 32)
{
  __shared__ float xlds[SECK * 32];
  __shared__ float wlds[4][2][16 * 64];

  const int t = threadIdx.x;
  const int l = t & 63;
  const int wq = t >> 6;
  const int jg = l & 7;        // W-address group
  const int ng = l >> 3;       // x-address group
  const int lrow = l >> 2;     // staging: row 0..15
  const int lk4 = (l & 3) * 4; // staging: k-offset 0,4,8,12

  float acc[8][4];
#pragma unroll
  for (int i = 0; i < 8; ++i)
#pragma unroll
    for (int q = 0; q < 4; ++q) acc[i][q] = 0.f;

  for (int sec = 0; sec < nsec; ++sec) {
    const int ks = kb0 + sec * SECK;
    __syncthreads();
    {
      const float* src = xT + (size_t)ks * 32;
      for (int i = t * 4; i < SECK * 32; i += 1024)
        *(float4*)(&xlds[i]) = *(const float4*)(src + i);
    }
    __syncthreads();

    const float* wsrc = Wrow + (size_t)(wq * 64 + lrow) * K + ks + lk4;
    const int nch = SECK / 16;

    float4 wr[4];
#pragma unroll
    for (int p = 0; p < 4; ++p) wr[p] = *(const float4*)(wsrc + (size_t)(p * 16) * K);
#pragma unroll
    for (int p = 0; p < 4; ++p) {
      float* wd = &wlds[wq][0][0];
      wd[(lk4 + 0) * 64 + p * 16 + lrow] = wr[p].x;
      wd[(lk4 + 1) * 64 + p * 16 + lrow] = wr[p].y;
      wd[(lk4 + 2) * 64 + p * 16 + lrow] = wr[p].z;
      wd[(lk4 + 3) * 64 + p * 16 + lrow] = wr[p].w;
    }
    int buf = 0;
    for (int c = 0; c < nch; ++c) {
      if (c + 1 < nch) {
#pragma unroll
        for (int p = 0; p < 4; ++p)
          wr[p] = *(const float4*)(wsrc + (size_t)(p * 16) * K + (c + 1) * 16);
      }
      const float* wb = &wlds[wq][buf][0];
      const float* xb = xlds + (size_t)(c * 16) * 32;
#pragma unroll
      for (int k = 0; k < 16; ++k) {
        float4 w0 = *(const float4*)(wb + k * 64 + jg * 8);
        float4 w1 = *(const float4*)(wb + k * 64 + jg * 8 + 4);
        float4 xv = *(const float4*)(xb + k * 32 + ng * 4);
        acc[0][0] = fmaf(w0.x, xv.x, acc[0][0]); acc[0][1] = fmaf(w0.x, xv.y, acc[0][1]);
        acc[0][2] = fmaf(w0.x, xv.z, acc[0][2]); acc[0][3] = fmaf(w0.x, xv.w, acc[0][3]);
        acc[1][0] = fmaf(w0.y, xv.x, acc[1][0]); acc[1][1] = fmaf(w0.y, xv.y, acc[1][1]);
        acc[1][2] = fmaf(w0.y, xv.z, acc[1][2]); acc[1][3] = fmaf(w0.y, xv.w, acc[1][3]);
        acc[2][0] = fmaf(w0.z, xv.x, acc[2][0]); acc[2][1] = fmaf(w0.z, xv.y, acc[2][1]);
        acc[2][2] = fmaf(w0.z, xv.z, acc[2][2]); acc[2][3] = fmaf(w0.z, xv.w, acc[2][3]);
        acc[3][0] = fmaf(w0.w, xv.x, acc[3][0]); acc[3][1] = fmaf(w0.w, xv.y, acc[3][1]);
        acc[3][2] = fmaf(w0.w, xv.z, acc[3][2]); acc[3][3] = fmaf(w0.w, xv.w, acc[3][3]);
        acc[4][0] = fmaf(w1.x, xv.x, acc[4][0]); acc[4][1] = fmaf(w1.x, xv.y, acc[4][1]);
        acc[4][2] = fmaf(w1.x, xv.z, acc[4][2]); acc[4][3] = fmaf(w1.x, xv.w, acc[4][3]);
        acc[5][0] = fmaf(w1.y, xv.x, acc[5][0]); acc[5][1] = fmaf(w1.y, xv.y, acc[5][1]);
        acc[5][2] = fmaf(w1.y, xv.z, acc[5][2]); acc[5][3] = fmaf(w1.y, xv.w, acc[5][3]);
        acc[6][0] = fmaf(w1.z, xv.x, acc[6][0]); acc[6][1] = fmaf(w1.z, xv.y, acc[6][1]);
        acc[6][2] = fmaf(w1.z, xv.z, acc[6][2]); acc[6][3] = fmaf(w1.z, xv.w, acc[6][3]);
        acc[7][0] = fmaf(w1.w, xv.x, acc[7][0]); acc[7][1] = fmaf(w1.w, xv.y, acc[7][1]);
        acc[7][2] = fmaf(w1.w, xv.z, acc[7][2]); acc[7][3] = fmaf(w1.w, xv.w, acc[7][3]);
      }
      if (c + 1 < nch) {
        float* wd = &wlds[wq][buf ^ 1][0];
#pragma unroll
        for (int p = 0; p < 4; ++p) {
          wd[(lk4 + 0) * 64 + p * 16 + lrow] = wr[p].x;
          wd[(lk4 + 1) * 64 + p * 16 + lrow] = wr[p].y;
          wd[(lk4 + 2) * 64 + p * 16 + lrow] = wr[p].z;
          wd[(lk4 + 3) * 64 + p * 16 + lrow] = wr[p].w;
        }
      }
      buf ^= 1;
    }
  }

#pragma unroll
  for (int i = 0; i < 8; ++i)
    *(float4*)(outP + (size_t)(wq * 64 + jg * 8 + i) * 32 + ng * 4) =
        make_float4(acc[i][0], acc[i][1], acc[i][2], acc[i][3]);
}

// ---------------------------------------------------------------------------
// gates: bx 0..95: hh (jt=bx%12, s=bx/12, K=1024 split 8x128) -> gHp[s]
//        bx 96..143: ih (jt=r%12, s=r/12, K=512 split 4x128) -> gIp[s]
// ---------------------------------------------------------------------------
__global__ __launch_bounds__(256, 2) void k_gates(
    const float* __restrict__ Wih, const float* __restrict__ Whh,
    const float* __restrict__ embX, const float* __restrict__ hT,
    float* __restrict__ gHp, float* __restrict__ gIp)
{
  const int bx = blockIdx.x;
  if (bx < 96) {
    const int jt = bx % 12, s = bx / 12;
    gemm_panel<128>(Whh + (size_t)jt * 256 * HID, HID, s * 128, 1, hT,
                    gHp + (size_t)s * (3072 * 32) + (size_t)jt * 256 * 32);
  } else {
    const int r = bx - 96;
    const int jt = r % 12, s = r / 12;
    gemm_panel<128>(Wih + (size_t)jt * 256 * EMB, EMB, s * 128, 1, embX,
                    gIp + (size_t)s * (3072 * 32) + (size_t)jt * 256 * 32);
  }
}

// ---------------------------------------------------------------------------
// combine: sum K-split partials + biases, GRU elementwise -> h2T[k][n]
// ---------------------------------------------------------------------------
__global__ __launch_bounds__(256) void k_combine(
    const float* __restrict__ gHp, const float* __restrict__ gIp,
    const float* __restrict__ bih, const float* __restrict__ bhh,
    const float* __restrict__ hT, float* __restrict__ h2T)
{
  int g = blockIdx.x * 256 + threadIdx.x;   // 32768
  int n = g & 31, i = g >> 5;
  float gir = bih[i], giz = bih[1024 + i], gin = bih[2048 + i];
#pragma unroll
  for (int s = 0; s < 4; ++s) {
    const float* P = gIp + (size_t)s * (3072 * 32);
    gir += P[(size_t)i * 32 + n];
    giz += P[(size_t)(1024 + i) * 32 + n];
    gin += P[(size_t)(2048 + i) * 32 + n];
  }
  float ghr = bhh[i], ghz = bhh[1024 + i], ghn = bhh[2048 + i];
#pragma unroll
  for (int s = 0; s < 8; ++s) {
    const float* P = gHp + (size_t)s * (3072 * 32);
    ghr += P[(size_t)i * 32 + n];
    ghz += P[(size_t)(1024 + i) * 32 + n];
    ghn += P[(size_t)(2048 + i) * 32 + n];
  }
  float r = 1.f / (1.f + expf(-(gir + ghr)));
  float z = 1.f / (1.f + expf(-(giz + ghz)));
  float nn = tanhf(gin + r * ghn);
  h2T[g] = (1.f - z) * nn + z * hT[g];
}

// ---------------------------------------------------------------------------
// logits: grid 125*NS WGs. jt = bx%125, s = bx/125. K=1024 split NS ways.
// ---------------------------------------------------------------------------
__global__ __launch_bounds__(256, 2) void k_logits(
    const float* __restrict__ Wout, const float* __restrict__ h2T,
    float* __restrict__ logitsP, int NS)
{
  const int jt = blockIdx.x % 125;
  const int s = blockIdx.x / 125;
  const int KperS = 1024 / NS;
  gemm_panel<256>(Wout + (size_t)jt * 256 * HID, HID, s * KperS, KperS / 256, h2T,
                  logitsP + (size_t)s * (NV * 32) + (size_t)jt * 256 * 32);
}

// ---------------------------------------------------------------------------
// reduce: 500 WGs. Sum NS partial slabs + bias for a 64-j chunk, transpose
// via LDS, write logitsN[n][v] (coalesced), compute lse partials per chunk.
// ---------------------------------------------------------------------------
__global__ __launch_bounds__(256) void k_reduce(
    const float* __restrict__ logitsP, const float* __restrict__ bout,
    float* __restrict__ logitsN, float* __restrict__ lsePart, int NS)
{
  __shared__ float tile[64][33];
  const int t = threadIdx.x;
  const int j0 = blockIdx.x * 64;

  {
    const int n = t & 31;
    const int jb = (t >> 5) * 8;
    float v[8];
#pragma unroll
    for (int i = 0; i < 8; ++i) v[i] = bout[j0 + jb + i];
    for (int s = 0; s < NS; ++s) {
      const float* P = logitsP + (size_t)s * (NV * 32) + (size_t)(j0 + jb) * 32 + n;
#pragma unroll
      for (int i = 0; i < 8; ++i) v[i] += P[(size_t)i * 32];
    }
#pragma unroll
    for (int i = 0; i < 8; ++i) tile[jb + i][n] = v[i];
  }
  __syncthreads();
  {
    const int jl = t & 63;
    const int wq = t >> 6;
#pragma unroll
    for (int q = 0; q < 8; ++q) {
      const int nn = wq * 8 + q;
      float val = tile[jl][nn];
      logitsN[(size_t)nn * NV + j0 + jl] = val;
      float m = val;
      m = fmaxf(m, __shfl_xor(m, 1, 64));
      m = fmaxf(m, __shfl_xor(m, 2, 64));
      m = fmaxf(m, __shfl_xor(m, 4, 64));
      m = fmaxf(m, __shfl_xor(m, 8, 64));
      m = fmaxf(m, __shfl_xor(m, 16, 64));
      m = fmaxf(m, __shfl_xor(m, 32, 64));
      float sx = expf(val - m);
      sx += __shfl_xor(sx, 1, 64);
      sx += __shfl_xor(sx, 2, 64);
      sx += __shfl_xor(sx, 4, 64);
      sx += __shfl_xor(sx, 8, 64);
      sx += __shfl_xor(sx, 16, 64);
      sx += __shfl_xor(sx, 32, 64);
      if (jl == 0) {
        lsePart[(size_t)blockIdx.x * 64 + nn * 2] = m;
        lsePart[(size_t)blockIdx.x * 64 + nn * 2 + 1] = sx;
      }
    }
  }
}

// ---------------------------------------------------------------------------
// topkA: 128 WGs (32 per batch). Finish lse, coalesced scan of contiguous
// candidate span of one row, per-thread sorted top-8, 8-round extraction.
// ---------------------------------------------------------------------------
__global__ __launch_bounds__(256) void k_topkA(
    const float* __restrict__ logitsN, const float* __restrict__ lsePart,
    const float* __restrict__ prev_vals, const int* __restrict__ prev_tok,
    const int* __restrict__ eosp, ull* __restrict__ top8A, int mode)
{
  const int t = threadIdx.x;
  const int b = blockIdx.x >> 5;
  const int c = blockIdx.x & 31;

  __shared__ float pm[32][8];
  __shared__ float ps[32][8];
  __shared__ float A[8];
  __shared__ ull wm[4];

  // phase 1: finish logsumexp over 500 partials
  {
    const int n8 = t & 7;
    const int grp = t >> 3;
    float m = -3.0e38f, s = 0.f;
    for (int p = grp; p < 500; p += 32) {
      float2 q = *(const float2*)(lsePart + (size_t)p * 64 + (b * 8 + n8) * 2);
      float Mx = fmaxf(m, q.x);
      s = s * expf(m - Mx) + q.y * expf(q.x - Mx);
      m = Mx;
    }
    pm[grp][n8] = m; ps[grp][n8] = s;
    __syncthreads();
    for (int off2 = 16; off2 >= 1; off2 >>= 1) {
      if (grp < off2) {
        float m1 = pm[grp][n8], s1 = ps[grp][n8];
        float m2 = pm[grp + off2][n8], s2 = ps[grp + off2][n8];
        float Mx = fmaxf(m1, m2);
        pm[grp][n8] = Mx;
        ps[grp][n8] = s1 * expf(m1 - Mx) + s2 * expf(m2 - Mx);
      }
      __syncthreads();
    }
    if (t < 8) A[t] = pm[0][t] + logf(ps[0][t]);
    __syncthreads();
  }

  const int eos = *eosp;

  ull t8[8];
#pragma unroll
  for (int j = 0; j < 8; ++j) t8[j] = 0ULL;

  if (mode == 1) {
    const int kb = c >> 2;
    const int v0 = (c & 3) * 8000;
    const bool fin = (prev_tok[b * 8 + kb] == eos);
    const float add = prev_vals[b * 8 + kb] - A[kb];
    const float* row = logitsN + (size_t)(b * 8 + kb) * NV;
    for (int v = v0 + t; v < v0 + 8000; v += 256) {
      float val;
      if (fin) val = (v == eos) ? 0.f : -1e30f;
      else val = row[v] + add;
      ull key = packkey(val, (unsigned)(kb * NV + v));
      if (key > t8[7]) {
        t8[7] = key;
#pragma unroll
        for (int q = 7; q >= 1; --q) {
          ull hi = umax64(t8[q - 1], t8[q]);
          ull lo = umin64(t8[q - 1], t8[q]);
          t8[q - 1] = hi; t8[q] = lo;
        }
      }
    }
  } else {
    const int v0 = c * 1000;
    const float add = -A[0];
    const float* row = logitsN + (size_t)(b * 8) * NV;
    for (int v = v0 + t; v < v0 + 1000; v += 256) {
      float val = row[v] + add;
      ull key = packkey(val, (unsigned)v);
      if (key > t8[7]) {
        t8[7] = key;
#pragma unroll
        for (int q = 7; q >= 1; --q) {
          ull hi = umax64(t8[q - 1], t8[q]);
          ull lo = umin64(t8[q - 1], t8[q]);
          t8[q - 1] = hi; t8[q] = lo;
        }
      }
    }
  }

  // 8-round exact extraction (keys unique)
  int pi = 0;
  for (int r = 0; r < 8; ++r) {
    ull cand = (pi < 8) ? t8[pi] : 0ULL;
#pragma unroll
    for (int off = 1; off < 64; off <<= 1) cand = umax64(cand, __shfl_xor(cand, off, 64));
    if ((t & 63) == 0) wm[t >> 6] = cand;
    __syncthreads();
    ull win = umax64(umax64(wm[0], wm[1]), umax64(wm[2], wm[3]));
    if (pi < 8 && t8[pi] == win) ++pi;
    if (t == 0) top8A[((size_t)b * 32 + c) * 8 + r] = win;
    __syncthreads();
  }
}

// ---------------------------------------------------------------------------
// topkB: 4 WGs. Merge 256 chunk winners -> final top-8 in order, commit beam
// state, gather histories (ping-pong), hidden columns, build embX for next.
// ---------------------------------------------------------------------------
__global__ __launch_bounds__(256) void k_topkB(
    const ull* __restrict__ top8A,
    float* __restrict__ prev_vals, int* __restrict__ prev_tok,
    const float* __restrict__ lp_src, float* __restrict__ lp_dst,
    const int* __restrict__ tok_src, int* __restrict__ tok_dst,
    const float* __restrict__ h2T, float* __restrict__ hT,
    const float* __restrict__ emb, float* __restrict__ embX,
    int step, int mode)
{
  const int t = threadIdx.x;
  const int b = blockIdx.x;
  __shared__ ull wm[4];
  __shared__ float vals8[8];
  __shared__ int tok8[8];
  __shared__ int which8[8];

  ull mykey = top8A[(size_t)b * 256 + t];
  int done = 0;
  for (int r = 0; r < 8; ++r) {
    ull cand = done ? 0ULL : mykey;
#pragma unroll
    for (int off = 1; off < 64; off <<= 1) cand = umax64(cand, __shfl_xor(cand, off, 64));
    if ((t & 63) == 0) wm[t >> 6] = cand;
    __syncthreads();
    ull win = umax64(umax64(wm[0], wm[1]), umax64(wm[2], wm[3]));
    if (!done && mykey == win) done = 1;
    if (t == 0) {
      unsigned idx = 0xFFFFFFFFu - (unsigned)(win & 0xFFFFFFFFull);
      unsigned u = (unsigned)(win >> 32);
      u = (u >> 31) ? (u ^ 0x80000000u) : ~u;
      vals8[r] = __uint_as_float(u);
      if (mode == 1) { tok8[r] = (int)(idx % NV); which8[r] = (int)(idx / NV); }
      else { tok8[r] = (int)idx; which8[r] = r; }
    }
    __syncthreads();
  }

  if (t < 8) {
    prev_vals[b * 8 + t] = vals8[t];
    prev_tok[b * 8 + t] = tok8[t];
  }
  for (int idx = t; idx < 512; idx += 256) {
    int j = idx >> 6;
    int tt = idx & 63;
    float lv; int tv;
    if (tt == step) { lv = vals8[j]; tv = tok8[j]; }
    else if (mode == 0) { lv = 0.f; tv = 0; }
    else {
      int w = which8[j];
      lv = lp_src[b * 512 + w * 64 + tt];
      tv = tok_src[b * 512 + w * 64 + tt];
    }
    lp_dst[b * 512 + idx] = lv;
    tok_dst[b * 512 + idx] = tv;
  }
  for (int idx = t; idx < 8192; idx += 256) {
    int kk = idx >> 3;
    int j = idx & 7;
    hT[kk * 32 + b * 8 + j] = h2T[kk * 32 + b * 8 + which8[j]];
  }
  // embX for next step: embX[k][b*8+j] = emb[tok8[j]][k]
  {
    int j = t >> 5;
    int kbase = (t & 31) * 16;
    const float* src = emb + (size_t)tok8[j] * EMB + kbase;
#pragma unroll
    for (int q = 0; q < 4; ++q) {
      float4 v = *(const float4*)(src + 4 * q);
      embX[(kbase + 4 * q + 0) * 32 + b * 8 + j] = v.x;
      embX[(kbase + 4 * q + 1) * 32 + b * 8 + j] = v.y;
      embX[(kbase + 4 * q + 2) * 32 + b * 8 + j] = v.z;
      embX[(kbase + 4 * q + 3) * 32 + b * 8 + j] = v.w;
    }
  }
}

// ---------------------------------------------------------------------------
// final: d_out = [lp_hist (2048 floats), tok_hist as floats (2048)]
// ---------------------------------------------------------------------------
__global__ void k_final(const float* __restrict__ lp_hist, const int* __restrict__ tok_hist,
                        float* __restrict__ out)
{
  int g = blockIdx.x * 256 + threadIdx.x;   // 4096
  if (g < 2048) out[g] = lp_hist[g];
  else out[g] = (float)tok_hist[g - 2048];
}

extern "C" void kernel_launch(void* const* d_in, const int* in_sizes, int n_in,
                              void* d_out, int out_size, void* d_ws, size_t ws_size,
                              hipStream_t stream)
{
  (void)in_sizes; (void)n_in; (void)out_size;
  const float* encoded   = (const float*)d_in[0];
  const float* embedding = (const float*)d_in[1];
  const float* Wih       = (const float*)d_in[2];
  const float* Whh       = (const float*)d_in[3];
  const float* bih       = (const float*)d_in[4];
  const float* bhh       = (const float*)d_in[5];
  const float* Wout      = (const float*)d_in[6];
  const float* bout      = (const float*)d_in[7];
  const int*   bosp      = (const int*)d_in[8];
  const int*   eosp      = (const int*)d_in[9];

  char* p = (char*)d_ws;
  size_t off = 0;
  auto ALLOC = [&](size_t bytes) -> void* {
    void* r = p + off;
    off += (bytes + 255) & ~(size_t)255;
    return r;
  };
  float* hT        = (float*)ALLOC((size_t)HID * 32 * 4);
  float* h2T       = (float*)ALLOC((size_t)HID * 32 * 4);
  float* embX      = (float*)ALLOC((size_t)EMB * 32 * 4);
  float* gHp       = (float*)ALLOC((size_t)8 * 3072 * 32 * 4);   // 3.15 MB
  float* gIp       = (float*)ALLOC((size_t)4 * 3072 * 32 * 4);   // 1.57 MB
  // logitsN overlays gHp+gIp (4.72 MB >= 4.10 MB). Safe: gHp/gIp are consumed
  // by k_combine before k_reduce writes logitsN; k_gates rewrites them fully
  // next step after topkA has consumed logitsN (stream-ordered).
  float* logitsN   = gHp;
  float* lsePart   = (float*)ALLOC((size_t)500 * 64 * 4);
  ull*   top8A     = (ull*)ALLOC((size_t)NB * 32 * 8 * 8);
  float* prev_vals = (float*)ALLOC(32 * 4);
  int*   prev_tok  = (int*)ALLOC(32 * 4);
  float* lp0       = (float*)ALLOC(2048 * 4);
  float* lp1       = (float*)ALLOC(2048 * 4);
  int*   tok0      = (int*)ALLOC(2048 * 4);
  int*   tok1      = (int*)ALLOC(2048 * 4);

  // logits partial slabs: pick largest NS in {4,2,1} that fits ws_size
  int NS = 4;
  if (off + (size_t)4 * NV * 32 * 4 > ws_size) NS = 2;
  if (off + (size_t)2 * NV * 32 * 4 > ws_size) NS = 1;
  float* logitsP = (float*)ALLOC((size_t)NS * NV * 32 * 4);

  k_prep<<<192, 256, 0, stream>>>(encoded, embedding, bosp, hT, embX);
  for (int t = 0; t < NT; ++t) {
    k_gates<<<144, 256, 0, stream>>>(Wih, Whh, embX, hT, gHp, gIp);
    k_combine<<<128, 256, 0, stream>>>(gHp, gIp, bih, bhh, hT, h2T);
    k_logits<<<125 * NS, 256, 0, stream>>>(Wout, h2T, logitsP, NS);
    k_reduce<<<500, 256, 0, stream>>>(logitsP, bout, logitsN, lsePart, NS);
    const int mode = (t == 0) ? 0 : 1;
    k_topkA<<<128, 256, 0, stream>>>(logitsN, lsePart, prev_vals, prev_tok, eosp, top8A, mode);
    float* lps = (t & 1) ? lp0 : lp1;
    float* lpd = (t & 1) ? lp1 : lp0;
    int*   tks = (t & 1) ? tok0 : tok1;
    int*   tkd = (t & 1) ? tok1 : tok0;
    k_topkB<<<NB, 256, 0, stream>>>(top8A, prev_vals, prev_tok, lps, lpd, tks, tkd,
                                    h2T, hT, embedding, embX, t, mode);
  }
  k_final<<<16, 256, 0, stream>>>(lp1, tok1, (float*)d_out);
}